// Round 2
// baseline (528.396 us; speedup 1.0000x reference)
//
#include <hip/hip_runtime.h>
#include <hip/hip_bf16.h>

typedef float  f32x4  __attribute__((ext_vector_type(4)));
typedef short  s16x8  __attribute__((ext_vector_type(8)));
typedef unsigned int u32x4 __attribute__((ext_vector_type(4)));

#define B_   4
#define SQ_  2048
#define SK_  2048
#define H_   16
#define D_   128
#define RS   (H_*D_)                 // 2048 floats per seq step
#define QSCALE 0.12751219658526f     // (1/sqrt(128)) * log2(e) -> log2 domain
#define KVB   64
#define QTILE 128
#define NQT   (SQ_/QTILE)            // 16 q-tiles per (b,h)
#define KB_BYTES  (KVB*D_*2)         // 16 KiB bf16 K tile
#define BUF_BYTES (2*KB_BYTES)       // 32 KiB: K tile + V^T tile

__device__ __forceinline__ unsigned pk_bf16(float lo, float hi) {
    unsigned r;
    asm("v_cvt_pk_bf16_f32 %0, %1, %2" : "=v"(r) : "v"(lo), "v"(hi));
    return r;
}
__device__ __forceinline__ void swap32u(unsigned &a, unsigned &b) {
    // a' = [a.lo32lanes | b.lo32lanes], b' = [a.hi32 | b.hi32]
    asm("v_permlane32_swap_b32 %0, %1" : "+v"(a), "+v"(b));
}
// K tile: [64 kv][128 d] bf16, row stride 256 B, XOR swizzle on 16B slots (T2)
__device__ __forceinline__ int kaddr(int row, int colb) {
    return row * 256 + (colb ^ ((row & 7) << 4));
}
// V^T tile: [128 d][64 kv] bf16, row stride 128 B (= 32 banks), swizzle on d
__device__ __forceinline__ int vaddr(int d, int colb) {
    return d * 128 + (colb ^ ((((d & 7) ^ ((d >> 3) & 7))) << 4));
}

__global__ __launch_bounds__(512, 4)
void fattn_fwd(const float* __restrict__ Qg, const float* __restrict__ Kg,
               const float* __restrict__ Vg, float* __restrict__ Og)
{
    __shared__ __align__(16) char smem[2 * BUF_BYTES];   // 64 KiB double buffer

    const int tid = threadIdx.x;
    const int w   = tid >> 6;        // wave 0..7, owns 16 q rows
    const int l   = tid & 63;
    const int g   = l >> 4;          // k-group 0..3
    const int q   = l & 15;          // q column within wave tile

    // ---- block decode: heavy-first (LPT) + XCD spread ----
    const int r   = blockIdx.x;                  // 0..1023
    const int qt  = (NQT - 1) - (r >> 6);        // ranks 0..15 -> qt 15..0
    const int i6  = r & 63;
    const int bh  = (i6 & 7) * 8 + (i6 >> 3);    // consecutive blocks -> different XCD
    const int b   = bh >> 4;
    const int h   = bh & 15;
    const int q0  = qt * QTILE;
    const int nt  = 2 * (qt + 1);                // KV tiles of 64

    const size_t base = ((size_t)b * SK_ * H_ + h) * D_;
    const float* Qp = Qg + base;
    const float* Kp = Kg + base;
    const float* Vp = Vg + base;
    float*       Op = Og + base;

    // ---- Q fragments (B operand of 16x16x32: col=q=l&15, k = 32*kt + 8*g + e) ----
    const int qrow = q0 + w * 16 + q;
    const float* qptr = Qp + (size_t)qrow * RS;
    s16x8 qf[4];
#pragma unroll
    for (int kt = 0; kt < 4; ++kt) {
        const float* p = qptr + 32 * kt + 8 * g;
        f32x4 a = *(const f32x4*)(p);
        f32x4 c = *(const f32x4*)(p + 4);
        u32x4 u;
        u[0] = pk_bf16(a[0] * QSCALE, a[1] * QSCALE);
        u[1] = pk_bf16(a[2] * QSCALE, a[3] * QSCALE);
        u[2] = pk_bf16(c[0] * QSCALE, c[1] * QSCALE);
        u[3] = pk_bf16(c[2] * QSCALE, c[3] * QSCALE);
        qf[kt] = __builtin_bit_cast(s16x8, u);
    }

    // ---- staging coordinates ----
    const int krow = tid >> 3;            // K: 1 kv row x 16 d per thread
    const int kc   = (tid & 7) * 16;
    const int vkv  = (tid >> 4) * 2;      // V: 2 kv rows x 8 d per thread
    const int vc   = (tid & 15) * 8;
    // pi: swap bits 2<->3 of kv (self-inverse) so PV's permlane32-only P-routing lines up
    const int ckv  = (vkv & ~12) | ((vkv & 4) << 1) | ((vkv & 8) >> 1);
    const float* kgp = Kp + (size_t)krow * RS + kc;
    const float* vgp = Vp + (size_t)vkv * RS + vc;

    auto stage = [&](char* dst, f32x4 kr0, f32x4 kr1, f32x4 kr2, f32x4 kr3,
                     f32x4 va0, f32x4 va1, f32x4 vb0, f32x4 vb1) {
        char* kb = dst;
        char* vb = dst + KB_BYTES;
        u32x4 u0, u1;
        u0[0] = pk_bf16(kr0[0], kr0[1]); u0[1] = pk_bf16(kr0[2], kr0[3]);
        u0[2] = pk_bf16(kr1[0], kr1[1]); u0[3] = pk_bf16(kr1[2], kr1[3]);
        u1[0] = pk_bf16(kr2[0], kr2[1]); u1[1] = pk_bf16(kr2[2], kr2[3]);
        u1[2] = pk_bf16(kr3[0], kr3[1]); u1[3] = pk_bf16(kr3[2], kr3[3]);
        *(u32x4*)(kb + kaddr(krow, kc * 2))      = u0;
        *(u32x4*)(kb + kaddr(krow, kc * 2 + 16)) = u1;
#pragma unroll
        for (int e = 0; e < 4; ++e) {
            *(unsigned*)(vb + vaddr(vc + e,     ckv * 2)) = pk_bf16(va0[e], vb0[e]);
            *(unsigned*)(vb + vaddr(vc + 4 + e, ckv * 2)) = pk_bf16(va1[e], vb1[e]);
        }
    };

    // ---- accumulators: O^T, lane(g,q): d = 16*ds + 4*g + rr, col q ----
    f32x4 oacc[8];
#pragma unroll
    for (int i = 0; i < 8; ++i) { oacc[i][0] = 0.f; oacc[i][1] = 0.f; oacc[i][2] = 0.f; oacc[i][3] = 0.f; }
    float m_run = -1e30f, l_run = 0.f;

    // ---- prologue: stage tile 0 into buffer 0 ----
    {
        f32x4 kr0 = *(const f32x4*)(kgp + 0);
        f32x4 kr1 = *(const f32x4*)(kgp + 4);
        f32x4 kr2 = *(const f32x4*)(kgp + 8);
        f32x4 kr3 = *(const f32x4*)(kgp + 12);
        f32x4 va0 = *(const f32x4*)(vgp + 0);
        f32x4 va1 = *(const f32x4*)(vgp + 4);
        f32x4 vb0 = *(const f32x4*)(vgp + RS);
        f32x4 vb1 = *(const f32x4*)(vgp + RS + 4);
        stage(smem, kr0, kr1, kr2, kr3, va0, va1, vb0, vb1);
    }
    __syncthreads();

    const int qminw = q0 + w * 16;
    const int qmaxw = qminw + 15;

    for (int t = 0; t < nt; ++t) {
        const int  nxt = t + 1;
        const bool have_next = nxt < nt;

        // T14: issue next tile's global loads BEFORE compute
        f32x4 kr0, kr1, kr2, kr3, va0, va1, vb0, vb1;
        if (have_next) {
            const float* kp2 = kgp + (size_t)nxt * KVB * RS;
            const float* vp2 = vgp + (size_t)nxt * KVB * RS;
            kr0 = *(const f32x4*)(kp2 + 0);
            kr1 = *(const f32x4*)(kp2 + 4);
            kr2 = *(const f32x4*)(kp2 + 8);
            kr3 = *(const f32x4*)(kp2 + 12);
            va0 = *(const f32x4*)(vp2 + 0);
            va1 = *(const f32x4*)(vp2 + 4);
            vb0 = *(const f32x4*)(vp2 + RS);
            vb1 = *(const f32x4*)(vp2 + RS + 4);
        }

        const int kvg = t * KVB;
        if (kvg <= qmaxw) {                       // wave-uniform causal skip
            const char* kb = smem + (t & 1) * BUF_BYTES;
            const char* vb = kb + KB_BYTES;

            // ---- QK^T (swapped): S^T[kv=64][q=16], 4 sub-blocks x 4 k-tiles ----
            f32x4 s[4];
#pragma unroll
            for (int kvs = 0; kvs < 4; ++kvs) { s[kvs][0]=0.f; s[kvs][1]=0.f; s[kvs][2]=0.f; s[kvs][3]=0.f; }
            __builtin_amdgcn_s_setprio(1);
#pragma unroll
            for (int kt = 0; kt < 4; ++kt) {
                const int colb = 64 * kt + 16 * g;
#pragma unroll
                for (int kvs = 0; kvs < 4; ++kvs) {
                    s16x8 ka = *(const s16x8*)(kb + kaddr(16 * kvs + q, colb));
                    s[kvs] = __builtin_amdgcn_mfma_f32_16x16x32_bf16(ka, qf[kt], s[kvs], 0, 0, 0);
                }
            }
            __builtin_amdgcn_s_setprio(0);

            // ---- causal mask: only diagonal tiles pay (wave-uniform branch) ----
            if (kvg + KVB - 1 > qminw) {
#pragma unroll
                for (int kvs = 0; kvs < 4; ++kvs)
#pragma unroll
                    for (int rr = 0; rr < 4; ++rr) {
                        const int kva = kvg + 16 * kvs + 4 * g + rr;
                        if (kva > qrow) s[kvs][rr] = -1e30f;
                    }
            }

            // ---- row max (q lane-local; reduce across the 4 g-groups) ----
            float pmax = -1e30f;
#pragma unroll
            for (int kvs = 0; kvs < 4; ++kvs)
#pragma unroll
                for (int rr = 0; rr < 4; ++rr) pmax = fmaxf(pmax, s[kvs][rr]);
            pmax = fmaxf(pmax, __shfl_xor(pmax, 16));
            pmax = fmaxf(pmax, __shfl_xor(pmax, 32));

            // ---- defer-max (T13, THR=8 in log2 domain) ----
            if (__any(pmax > m_run + 8.0f)) {
                const float mnew = fmaxf(m_run, pmax);
                const float f = exp2f(m_run - mnew);
                m_run = mnew;
                l_run *= f;
#pragma unroll
                for (int i = 0; i < 8; ++i) {
                    oacc[i][0] *= f; oacc[i][1] *= f; oacc[i][2] *= f; oacc[i][3] *= f;
                }
            }

            // ---- exp2 + row sum ----
            float psum = 0.f;
#pragma unroll
            for (int kvs = 0; kvs < 4; ++kvs)
#pragma unroll
                for (int rr = 0; rr < 4; ++rr) {
                    s[kvs][rr] = exp2f(s[kvs][rr] - m_run);
                    psum += s[kvs][rr];
                }
            psum += __shfl_xor(psum, 16);
            psum += __shfl_xor(psum, 32);
            l_run += psum;

            // ---- T12: P -> bf16 PV B-operand, permlane32-only routing ----
            // pb[kt2] word m: kv = 32*kt2 + pi(8g + 2m + b); V staged at col pi(kv).
            s16x8 pb[2];
#pragma unroll
            for (int kt2 = 0; kt2 < 2; ++kt2) {
                unsigned A0 = pk_bf16(s[2 * kt2][0],     s[2 * kt2][1]);
                unsigned A1 = pk_bf16(s[2 * kt2][2],     s[2 * kt2][3]);
                unsigned B0 = pk_bf16(s[2 * kt2 + 1][0], s[2 * kt2 + 1][1]);
                unsigned B1 = pk_bf16(s[2 * kt2 + 1][2], s[2 * kt2 + 1][3]);
                swap32u(A0, B0);
                swap32u(A1, B1);
                u32x4 p; p[0] = A0; p[1] = A1; p[2] = B0; p[3] = B1;
                pb[kt2] = __builtin_bit_cast(s16x8, p);
            }

            // ---- PV: O^T[d][q] += V^T[d][kv] * P^T[kv][q] ----
            __builtin_amdgcn_s_setprio(1);
#pragma unroll
            for (int ds = 0; ds < 8; ++ds) {
                const int d = 16 * ds + q;
#pragma unroll
                for (int kt2 = 0; kt2 < 2; ++kt2) {
                    s16x8 va = *(const s16x8*)(vb + vaddr(d, 64 * kt2 + 16 * g));
                    oacc[ds] = __builtin_amdgcn_mfma_f32_16x16x32_bf16(va, pb[kt2], oacc[ds], 0, 0, 0);
                }
            }
            __builtin_amdgcn_s_setprio(0);
        }

        __syncthreads();
        if (have_next) {
            stage(smem + (nxt & 1) * BUF_BYTES, kr0, kr1, kr2, kr3, va0, va1, vb0, vb1);
        }
        __syncthreads();
    }

    // ---- epilogue: O[q][d] = O^T_acc / l ----
    const float inv = 1.0f / l_run;
    float* op = Op + (size_t)qrow * RS;
#pragma unroll
    for (int ds = 0; ds < 8; ++ds) {
        f32x4 o4;
        o4[0] = oacc[ds][0] * inv;
        o4[1] = oacc[ds][1] * inv;
        o4[2] = oacc[ds][2] * inv;
        o4[3] = oacc[ds][3] * inv;
        *(f32x4*)(op + 16 * ds + 4 * g) = o4;
    }
}

extern "C" void kernel_launch(void* const* d_in, const int* in_sizes, int n_in,
                              void* d_out, int out_size, void* d_ws, size_t ws_size,
                              hipStream_t stream) {
    const float* Q = (const float*)d_in[0];
    const float* K = (const float*)d_in[1];
    const float* V = (const float*)d_in[2];
    float* O = (float*)d_out;
    (void)in_sizes; (void)n_in; (void)out_size; (void)d_ws; (void)ws_size;
    dim3 grid(B_ * H_ * NQT);        // 1024 blocks, heavy-first order
    dim3 block(512);
    hipLaunchKernelGGL(fattn_fwd, grid, block, 0, stream, Q, K, V, O);
}